// Round 4
// baseline (173.853 us; speedup 1.0000x reference)
//
#include <hip/hip_runtime.h>
#include <hip/hip_bf16.h>

#define IN_CH 256
#define OUT_CH 128
#define NCAT 256          // concatenated output channels (sup | gat)
#define CAP 64            // bucket capacity per row (Poisson(16): P(>64) ~ 1e-13)
#define NSLICE 8          // one per XCD; slice array = N*64B = 3.2MB < 4MB L2

typedef __attribute__((ext_vector_type(8))) short bf16x8;
typedef __attribute__((ext_vector_type(4))) float f32x4;

__device__ __forceinline__ unsigned short f2bf(float f) {
  unsigned int u = __builtin_bit_cast(unsigned int, f);
  u += 0x7FFFu + ((u >> 16) & 1u);           // round-to-nearest-even
  return (unsigned short)(u >> 16);
}
__device__ __forceinline__ unsigned int pack2bf(float a, float b) {
  return (unsigned int)f2bf(a) | ((unsigned int)f2bf(b) << 16);
}
__device__ __forceinline__ float bflo(unsigned int u) {
  return __builtin_bit_cast(float, u << 16);
}
__device__ __forceinline__ float bfhi(unsigned int u) {
  return __builtin_bit_cast(float, u & 0xFFFF0000u);
}

// ---------------------------------------------------------------------------
// WcatT[c][k] bf16, c in [0,256): c<128 -> w[k][c], c>=128 -> gw[k][c-128].
// ---------------------------------------------------------------------------
__global__ __launch_bounds__(256) void build_wcat(
    const float* __restrict__ w, const float* __restrict__ gw,
    unsigned short* __restrict__ wcatT) {
  const int c = blockIdx.x;      // 0..255
  const int k = threadIdx.x;     // 0..255
  const float v = (c < 128) ? w[(size_t)k * 128 + c] : gw[(size_t)k * 128 + (c - 128)];
  wcatT[(size_t)c * 256 + k] = f2bf(v);
}

// ---------------------------------------------------------------------------
// MFMA GEMM: comb = bf16(x) @ Wcat, written XCD-SLICED:
//   slice s (s=0..7) = array of N rows x 64 B; holds channel-pairs
//   p in [8s, 8s+8), each pair packed 8 B: [sup2p,sup2p+1,gat2p,gat2p+1] bf16.
// ---------------------------------------------------------------------------
#define BM 128
#define BK 64
#define LDSTRIDE 144   // bytes per LDS row (128 data + 16 pad)

__global__ __launch_bounds__(512) void gemm_mfma(
    const float* __restrict__ x, const unsigned short* __restrict__ wcatT,
    char* __restrict__ comb, int nrows) {
  __shared__ char As[BM * LDSTRIDE];     // 18432 B
  __shared__ char Bs[NCAT * LDSTRIDE];   // 36864 B

  const int t = threadIdx.x;
  const int lane = t & 63;
  const int wv = t >> 6;          // 0..7
  const int wr = wv >> 2;         // 0..1  (M)
  const int wc = wv & 3;          // 0..3  (N)
  const int blockRow = blockIdx.x * BM;
  const int lrow = lane & 15;
  const int klane = lane >> 4;    // 0..3

  f32x4 acc[4][4];
#pragma unroll
  for (int m = 0; m < 4; ++m)
#pragma unroll
    for (int n = 0; n < 4; ++n) acc[m][n] = (f32x4){0.f, 0.f, 0.f, 0.f};

  const int arow = t >> 2;              // 0..127
  const int aseg = t & 3;               // 16 f32 each
  const int agrow = blockRow + arow;
  const bool aok = (agrow < nrows);
  const float* xrow = x + (size_t)agrow * IN_CH;

  const int bc = t >> 1;                // 0..255
  const int bhalf = t & 1;              // 0/1 (32 bf16 each)

  for (int kt = 0; kt < IN_CH; kt += BK) {
    {
      float4 v0 = make_float4(0, 0, 0, 0), v1 = v0, v2 = v0, v3 = v0;
      if (aok) {
        const float* p = xrow + kt + aseg * 16;
        v0 = *(const float4*)(p + 0);
        v1 = *(const float4*)(p + 4);
        v2 = *(const float4*)(p + 8);
        v3 = *(const float4*)(p + 12);
      }
      uint4 pk0, pk1;
      pk0.x = pack2bf(v0.x, v0.y); pk0.y = pack2bf(v0.z, v0.w);
      pk0.z = pack2bf(v1.x, v1.y); pk0.w = pack2bf(v1.z, v1.w);
      pk1.x = pack2bf(v2.x, v2.y); pk1.y = pack2bf(v2.z, v2.w);
      pk1.z = pack2bf(v3.x, v3.y); pk1.w = pack2bf(v3.z, v3.w);
      char* dst = As + arow * LDSTRIDE + aseg * 32;
      *(uint4*)(dst + 0)  = pk0;
      *(uint4*)(dst + 16) = pk1;
    }
    {
      const char* src = (const char*)wcatT + (size_t)bc * 512 + kt * 2 + bhalf * 64;
      char* dst = Bs + bc * LDSTRIDE + bhalf * 64;
#pragma unroll
      for (int j = 0; j < 4; ++j)
        *(uint4*)(dst + j * 16) = *(const uint4*)(src + j * 16);
    }
    __syncthreads();

#pragma unroll
    for (int kk = 0; kk < 2; ++kk) {
      bf16x8 af[4], bfm[4];
#pragma unroll
      for (int m = 0; m < 4; ++m)
        af[m] = *(const bf16x8*)(As + (wr * 64 + m * 16 + lrow) * LDSTRIDE + kk * 64 + klane * 16);
#pragma unroll
      for (int n = 0; n < 4; ++n)
        bfm[n] = *(const bf16x8*)(Bs + (wc * 64 + n * 16 + lrow) * LDSTRIDE + kk * 64 + klane * 16);
#pragma unroll
      for (int m = 0; m < 4; ++m)
#pragma unroll
        for (int n = 0; n < 4; ++n)
          acc[m][n] = __builtin_amdgcn_mfma_f32_16x16x32_bf16(af[m], bfm[n], acc[m][n], 0, 0, 0);
    }
    __syncthreads();
  }

  // D[row][col]: col=lane&15, row=(lane>>4)*4+j (m89-verified)
#pragma unroll
  for (int m = 0; m < 4; ++m) {
#pragma unroll
    for (int n = 0; n < 4; ++n) {
#pragma unroll
      for (int j = 0; j < 4; ++j) {
        const int grow = blockRow + wr * 64 + m * 16 + klane * 4 + j;
        if (grow < nrows) {
          const int gcol = wc * 64 + n * 16 + lrow;
          const int ch = gcol & 127;
          const int isg = gcol >> 7;       // 0=sup, 1=gat
          const int p = ch >> 1;           // pair 0..63
          const int s = p >> 3;            // slice 0..7
          const int q = p & 7;             // pair within slice
          char* dst = comb + ((size_t)s * nrows + grow) * 64 + q * 8 + isg * 4 + (ch & 1) * 2;
          *(unsigned short*)dst = f2bf(acc[m][n][j]);
        }
      }
    }
  }
}

// ---------------------------------------------------------------------------
// Bucket build: bucket4[r*CAP+idx] = {col:16 | bf16(val):16}. N<65536 so col
// fits 16 bits.
// ---------------------------------------------------------------------------
__global__ __launch_bounds__(256) void build_buckets(
    const int* __restrict__ rows, const int* __restrict__ cols,
    const float* __restrict__ vals, int* __restrict__ cnt,
    unsigned* __restrict__ bucket4, int E) {
  const int e = blockIdx.x * 256 + threadIdx.x;
  if (e < E) {
    const int r = rows[e];
    const int idx = atomicAdd(&cnt[r], 1);
    if (idx < CAP)
      bucket4[(size_t)r * CAP + idx] =
          ((unsigned)cols[e] << 16) | (unsigned)f2bf(vals[e]);
  }
}

// ---------------------------------------------------------------------------
// Sliced SpMM + gate. blockIdx.x & 7 selects the channel slice (-> XCD via
// round-robin dispatch), so each block's gathers hit a 3.2MB L2-resident
// slice array. 8-lane group per edge (64B row-slice), 8 edges per load
// instruction, 2 loads in flight; 3x shfl_xor reduce; lanes 0..7 write.
// ---------------------------------------------------------------------------
#define ROWS_PER_WAVE 8

__global__ __launch_bounds__(256) void spmm_sliced(
    const unsigned* __restrict__ bucket4, const int* __restrict__ cnt,
    const char* __restrict__ comb, float* __restrict__ out, int nrows) {
  const int slice = blockIdx.x & 7;
  const int rowgroup = blockIdx.x >> 3;
  const int wv = threadIdx.x >> 6;
  const int lane = threadIdx.x & 63;
  const int sub = lane >> 3;       // edge subgroup 0..7
  const int q = lane & 7;          // channel-pair within slice
  const char* sbase = comb + (size_t)slice * nrows * 64;

  const int r0 = rowgroup * (4 * ROWS_PER_WAVE) + wv * ROWS_PER_WAVE;

  for (int i = 0; i < ROWS_PER_WAVE; ++i) {
    const int r = r0 + i;
    if (r >= nrows) return;
    const int deg = min(cnt[r], CAP);
    float s0 = 0.f, s1 = 0.f, g0 = 0.f, g1 = 0.f;

    if (deg > 0) {
      const unsigned ent = (lane < deg) ? bucket4[(size_t)r * CAP + lane] : 0u;
      for (int d = 0; d < deg; d += 16) {
        const int d0 = d + sub;
        const int d1 = d + 8 + sub;
        const unsigned e0 = (unsigned)__shfl((int)ent, d0 < deg ? d0 : deg - 1);
        const unsigned e1 = (unsigned)__shfl((int)ent, d1 < deg ? d1 : deg - 1);
        const uint2 q0 = *(const uint2*)(sbase + (size_t)(e0 >> 16) * 64 + q * 8);
        const uint2 q1 = *(const uint2*)(sbase + (size_t)(e1 >> 16) * 64 + q * 8);
        const float v0 = (d0 < deg) ? bflo(e0) : 0.f;
        const float v1 = (d1 < deg) ? bflo(e1) : 0.f;
        s0 += v0 * bflo(q0.x);  s1 += v0 * bfhi(q0.x);
        g0 += v0 * bflo(q0.y);  g1 += v0 * bfhi(q0.y);
        s0 += v1 * bflo(q1.x);  s1 += v1 * bfhi(q1.x);
        g0 += v1 * bflo(q1.y);  g1 += v1 * bfhi(q1.y);
      }
      // reduce across the 8 edge-subgroups (stride-8 lanes share (lane&7))
#pragma unroll
      for (int m = 8; m <= 32; m <<= 1) {
        s0 += __shfl_xor(s0, m);  s1 += __shfl_xor(s1, m);
        g0 += __shfl_xor(g0, m);  g1 += __shfl_xor(g1, m);
      }
    }
    const float o0 = s0 / (1.f + __expf(-g0));
    const float o1 = s1 / (1.f + __expf(-g1));
    if (lane < 8) {
      const int p = slice * 8 + q;     // global channel pair
      *(float2*)&out[(size_t)r * OUT_CH + p * 2] = make_float2(o0, o1);
    }
  }
}

extern "C" void kernel_launch(void* const* d_in, const int* in_sizes, int n_in,
                              void* d_out, int out_size, void* d_ws, size_t ws_size,
                              hipStream_t stream) {
  const float* x  = (const float*)d_in[0];
  const int*   er = (const int*)d_in[1];
  const int*   ec = (const int*)d_in[2];
  const float* ev = (const float*)d_in[3];
  const float* w  = (const float*)d_in[4];
  const float* gw = (const float*)d_in[5];
  float* out = (float*)d_out;

  const int N = in_sizes[0] / IN_CH;   // 50000
  const int E = in_sizes[1];           // 800000

  // workspace: comb [8 slices * N*64 B] | wcatT [128 KB] | cnt [N*4] | bucket4 [N*CAP*4]
  char* ws = (char*)d_ws;
  char* comb = ws;
  size_t off = (size_t)NSLICE * N * 64;
  unsigned short* wcatT = (unsigned short*)(ws + off);  off += 256 * 256 * 2;
  int* cnt = (int*)(ws + off);                          off += (size_t)N * 4;
  unsigned* bucket4 = (unsigned*)(ws + off);

  hipMemsetAsync(cnt, 0, (size_t)N * 4, stream);

  build_wcat<<<256, 256, 0, stream>>>(w, gw, wcatT);

  build_buckets<<<(E + 255) / 256, 256, 0, stream>>>(er, ec, ev, cnt, bucket4, E);

  const int gemmBlocks = (N + BM - 1) / BM;
  gemm_mfma<<<gemmBlocks, 512, 0, stream>>>(x, wcatT, comb, N);

  const int rowsPerBlock = 4 * ROWS_PER_WAVE;  // 32
  const int rowGroups = (N + rowsPerBlock - 1) / rowsPerBlock;
  spmm_sliced<<<rowGroups * NSLICE, 256, 0, stream>>>(bucket4, cnt, comb, out, N);
}

// Round 5
// 135.313 us; speedup vs baseline: 1.2848x; 1.2848x over previous
//
#include <hip/hip_runtime.h>
#include <hip/hip_bf16.h>

#define IN_CH 256
#define OUT_CH 128
#define NCAT 256          // concatenated output channels (sup | gat)
#define CAP 64            // bucket capacity per row (Poisson(16): P(>64) ~ 1e-13)

typedef __attribute__((ext_vector_type(8))) short bf16x8;
typedef __attribute__((ext_vector_type(4))) float f32x4;

__device__ __forceinline__ unsigned short f2bf(float f) {
  unsigned int u = __builtin_bit_cast(unsigned int, f);
  u += 0x7FFFu + ((u >> 16) & 1u);           // round-to-nearest-even
  return (unsigned short)(u >> 16);
}
__device__ __forceinline__ unsigned int pack2bf(float a, float b) {
  return (unsigned int)f2bf(a) | ((unsigned int)f2bf(b) << 16);
}
__device__ __forceinline__ float bflo(unsigned int u) {
  return __builtin_bit_cast(float, u << 16);
}
__device__ __forceinline__ float bfhi(unsigned int u) {
  return __builtin_bit_cast(float, u & 0xFFFF0000u);
}

// ---------------------------------------------------------------------------
// Init: cnt = 0 (blocks [0,cntBlocks)) and WcatT build (next 256 blocks).
// WcatT[c][k] bf16, c in [0,256): c<128 -> w[k][c], c>=128 -> gw[k][c-128].
// ---------------------------------------------------------------------------
__global__ __launch_bounds__(256) void init_and_wcat(
    const float* __restrict__ w, const float* __restrict__ gw,
    unsigned short* __restrict__ wcatT, int* __restrict__ cnt,
    int nrows, int cntBlocks) {
  const int b = blockIdx.x;
  if (b < cntBlocks) {
    const int i = b * 256 + threadIdx.x;
    if (i < nrows) cnt[i] = 0;
  } else {
    const int c = b - cntBlocks;          // 0..255
    const int k = threadIdx.x;            // 0..255
    const float v = (c < 128) ? w[(size_t)k * 128 + c]
                              : gw[(size_t)k * 128 + (c - 128)];
    wcatT[(size_t)c * 256 + k] = f2bf(v);
  }
}

// ---------------------------------------------------------------------------
// Fat kernel: blocks [0,gemmBlocks) do MFMA GEMM tiles (128x128 of comb),
// blocks [gemmBlocks, +bktBlocks) scatter edges into per-row buckets.
// The two roles are data-independent; bucket work hides under GEMM.
//
// comb layout (round-3 verified): row r = 512 B; channel-pair p at byte 8p:
//   [sup_{2p}, sup_{2p+1}, gat_{2p}, gat_{2p+1}] bf16  -> spmm gathers 1
//   dwordx2 per lane.
// ---------------------------------------------------------------------------
#define BM 128
#define BK 64
#define LDSTRIDE 144   // bytes per LDS row (128 data + 16 pad)

__global__ __launch_bounds__(512) void gemm_and_buckets(
    const float* __restrict__ x, const unsigned short* __restrict__ wcatT,
    char* __restrict__ comb, int nrows,
    const int* __restrict__ er, const int* __restrict__ ec,
    const float* __restrict__ ev, int* __restrict__ cnt,
    unsigned* __restrict__ bucket4, int E, int gemmBlocks, int bktBlocks) {
  __shared__ char As[BM * LDSTRIDE];     // 18432 B
  __shared__ char Bs[128 * LDSTRIDE];    // 18432 B

  if (blockIdx.x >= gemmBlocks) {
    // ---- bucket role: bucket4[r*CAP+idx] = {col:16 | bf16(val):16} ----
    const int stride = bktBlocks * 512;
    for (int e = (blockIdx.x - gemmBlocks) * 512 + threadIdx.x; e < E; e += stride) {
      const int r = er[e];
      const int idx = atomicAdd(&cnt[r], 1);
      if (idx < CAP)
        bucket4[(size_t)r * CAP + idx] =
            ((unsigned)ec[e] << 16) | (unsigned)f2bf(ev[e]);
    }
    return;
  }

  // ---- GEMM role: tile = rows [blockRow,+128) x NCAT-cols [colBase,+128) ----
  const int t = threadIdx.x;
  const int lane = t & 63;
  const int wv = t >> 6;          // 0..7
  const int wr = wv >> 2;         // 0..1  (M half, 64 rows)
  const int wc = wv & 3;          // 0..3  (N slice, 32 cols)
  const int blockRow = (blockIdx.x >> 1) * BM;
  const int colBase = (blockIdx.x & 1) * 128;
  const int lrow = lane & 15;
  const int klane = lane >> 4;    // 0..3

  f32x4 acc[4][2];
#pragma unroll
  for (int m = 0; m < 4; ++m)
#pragma unroll
    for (int n = 0; n < 2; ++n) acc[m][n] = (f32x4){0.f, 0.f, 0.f, 0.f};

  const int arow = t >> 2;              // 0..127
  const int aseg = t & 3;               // 16 f32 each
  const int agrow = blockRow + arow;
  const bool aok = (agrow < nrows);
  const float* xrow = x + (size_t)agrow * IN_CH;

  for (int kt = 0; kt < IN_CH; kt += BK) {
    // stage A: 128 rows x 64 k, f32 -> bf16
    {
      float4 v0 = make_float4(0, 0, 0, 0), v1 = v0, v2 = v0, v3 = v0;
      if (aok) {
        const float* p = xrow + kt + aseg * 16;
        v0 = *(const float4*)(p + 0);
        v1 = *(const float4*)(p + 4);
        v2 = *(const float4*)(p + 8);
        v3 = *(const float4*)(p + 12);
      }
      uint4 pk0, pk1;
      pk0.x = pack2bf(v0.x, v0.y); pk0.y = pack2bf(v0.z, v0.w);
      pk0.z = pack2bf(v1.x, v1.y); pk0.w = pack2bf(v1.z, v1.w);
      pk1.x = pack2bf(v2.x, v2.y); pk1.y = pack2bf(v2.z, v2.w);
      pk1.z = pack2bf(v3.x, v3.y); pk1.w = pack2bf(v3.z, v3.w);
      char* dst = As + arow * LDSTRIDE + aseg * 32;
      *(uint4*)(dst + 0)  = pk0;
      *(uint4*)(dst + 16) = pk1;
    }
    // stage B: 128 cols x 64 k bf16 from wcatT (already converted)
    {
      const int c = t >> 2;             // 0..127
      const int seg = t & 3;            // 32 B each
      const char* src = (const char*)wcatT + (size_t)(colBase + c) * 512 + kt * 2 + seg * 32;
      char* dst = Bs + c * LDSTRIDE + seg * 32;
      *(uint4*)(dst + 0)  = *(const uint4*)(src + 0);
      *(uint4*)(dst + 16) = *(const uint4*)(src + 16);
    }
    __syncthreads();

#pragma unroll
    for (int kk = 0; kk < 2; ++kk) {
      bf16x8 af[4], bfm[2];
#pragma unroll
      for (int m = 0; m < 4; ++m)
        af[m] = *(const bf16x8*)(As + (wr * 64 + m * 16 + lrow) * LDSTRIDE + kk * 64 + klane * 16);
#pragma unroll
      for (int n = 0; n < 2; ++n)
        bfm[n] = *(const bf16x8*)(Bs + (wc * 32 + n * 16 + lrow) * LDSTRIDE + kk * 64 + klane * 16);
#pragma unroll
      for (int m = 0; m < 4; ++m)
#pragma unroll
        for (int n = 0; n < 2; ++n)
          acc[m][n] = __builtin_amdgcn_mfma_f32_16x16x32_bf16(af[m], bfm[n], acc[m][n], 0, 0, 0);
    }
    __syncthreads();
  }

  // epilogue: D[row][col]: col=lane&15, row=(lane>>4)*4+j (m89-verified)
#pragma unroll
  for (int m = 0; m < 4; ++m) {
#pragma unroll
    for (int n = 0; n < 2; ++n) {
#pragma unroll
      for (int j = 0; j < 4; ++j) {
        const int grow = blockRow + wr * 64 + m * 16 + klane * 4 + j;
        if (grow < nrows) {
          const int gcol = colBase + wc * 32 + n * 16 + lrow;   // 0..255
          const int ch = gcol & 127;
          const int isg = gcol >> 7;
          const int byteoff = (ch >> 1) * 8 + isg * 4 + (ch & 1) * 2;
          *(unsigned short*)(comb + (size_t)grow * 512 + byteoff) = f2bf(acc[m][n][j]);
        }
      }
    }
  }
}

// ---------------------------------------------------------------------------
// Fused SpMM x2 + sigmoid gate (round-3 verified form, 57 us).
// One wave per row; lane covers 2 channel-pairs (8 B). Whole edge set loaded
// in ONE coalesced read, then chunks of 8 independent gathers in flight.
// ---------------------------------------------------------------------------
__global__ __launch_bounds__(256) void spmm_fused(
    const unsigned* __restrict__ bucket4, const int* __restrict__ cnt,
    const char* __restrict__ comb, float* __restrict__ out, int nrows) {
  const int wid = (int)((blockIdx.x * 256 + threadIdx.x) >> 6);
  const int lane = threadIdx.x & 63;
  if (wid >= nrows) return;

  const int deg = min(cnt[wid], CAP);
  float s0 = 0.f, s1 = 0.f, g0 = 0.f, g1 = 0.f;

  if (deg > 0) {
    const unsigned my = bucket4[(size_t)wid * CAP + lane];   // lane d = edge d
    for (int d = 0; d < deg; d += 8) {
      unsigned cj[8]; float vj[8]; uint2 q[8];
#pragma unroll
      for (int j = 0; j < 8; ++j) {
        const int dj = d + j;
        const int ds = dj < deg ? dj : deg - 1;          // clamp (dup addr ~free)
        const unsigned ent = (unsigned)__shfl((int)my, ds);
        cj[j] = ent >> 16;
        vj[j] = (dj < deg) ? bflo(ent) : 0.f;
      }
#pragma unroll
      for (int j = 0; j < 8; ++j)
        q[j] = *(const uint2*)(comb + (size_t)cj[j] * 512 + lane * 8);
#pragma unroll
      for (int j = 0; j < 8; ++j) {
        s0 += vj[j] * bflo(q[j].x);  s1 += vj[j] * bfhi(q[j].x);
        g0 += vj[j] * bflo(q[j].y);  g1 += vj[j] * bfhi(q[j].y);
      }
    }
  }
  const float o0 = s0 / (1.f + __expf(-g0));
  const float o1 = s1 / (1.f + __expf(-g1));
  *(float2*)&out[(size_t)wid * OUT_CH + lane * 2] = make_float2(o0, o1);
}

extern "C" void kernel_launch(void* const* d_in, const int* in_sizes, int n_in,
                              void* d_out, int out_size, void* d_ws, size_t ws_size,
                              hipStream_t stream) {
  const float* x  = (const float*)d_in[0];
  const int*   er = (const int*)d_in[1];
  const int*   ec = (const int*)d_in[2];
  const float* ev = (const float*)d_in[3];
  const float* w  = (const float*)d_in[4];
  const float* gw = (const float*)d_in[5];
  float* out = (float*)d_out;

  const int N = in_sizes[0] / IN_CH;   // 50000
  const int E = in_sizes[1];           // 800000

  // workspace: comb [N*512 B] | wcatT [128 KB] | cnt [N*4] | bucket4 [N*CAP*4]
  char* ws = (char*)d_ws;
  char* comb = ws;
  size_t off = (size_t)N * 512;
  unsigned short* wcatT = (unsigned short*)(ws + off);  off += 256 * 256 * 2;
  int* cnt = (int*)(ws + off);                          off += (size_t)N * 4;
  unsigned* bucket4 = (unsigned*)(ws + off);

  // 1) init: cnt=0 + wcat build
  const int cntBlocks = (N + 255) / 256;
  init_and_wcat<<<cntBlocks + 256, 256, 0, stream>>>(w, gw, wcatT, cnt, N, cntBlocks);

  // 2) fused GEMM + bucket scatter
  const int gemmBlocks = ((N + BM - 1) / BM) * 2;   // 2 col-halves
  const int bktBlocks = 256;
  gemm_and_buckets<<<gemmBlocks + bktBlocks, 512, 0, stream>>>(
      x, wcatT, comb, N, er, ec, ev, cnt, bucket4, E, gemmBlocks, bktBlocks);

  // 3) fused SpMM + gate
  const int blocks = (N + 3) / 4;   // 4 waves / 256-thr block
  spmm_fused<<<blocks, 256, 0, stream>>>(bucket4, cnt, comb, out, N);
}